// Round 10
// baseline (116.506 us; speedup 1.0000x reference)
//
#include <hip/hip_runtime.h>
#include <hip/hip_bf16.h>
#include <stdint.h>

#define NH 16
#define HID 1024
#define HD 64
#define NB 4
#define SS 1024
#define MTOT (NB*SS)   // 4096

typedef __attribute__((ext_vector_type(8))) short bf16x8;
typedef __attribute__((ext_vector_type(4))) float f32x4;
typedef __attribute__((ext_vector_type(16))) float f32x16;

#define LOG2E 1.44269504088896f

__device__ __forceinline__ unsigned short f2bf(float f) {
  union { float f; unsigned u; } v; v.f = f;
  unsigned u = v.u;
  return (unsigned short)((u + 0x7FFFu + ((u >> 16) & 1u)) >> 16);
}

__device__ __forceinline__ unsigned cvtpk(float lo, float hi) {
  unsigned r;
  asm("v_cvt_pk_bf16_f32 %0, %1, %2" : "=v"(r) : "v"(lo), "v"(hi));
  return r;
}

__device__ __forceinline__ void pl32swap(unsigned &a, unsigned &b) {
  asm("v_permlane32_swap_b32 %0, %1" : "+v"(a), "+v"(b));
}

__device__ __forceinline__ float exp2fast(float x) {
  float r;
  asm("v_exp_f32 %0, %1" : "=v"(r) : "v"(x));
  return r;
}

__device__ __forceinline__ void async16(void* lds, const void* g) {
  __builtin_amdgcn_global_load_lds(
      (const __attribute__((address_space(1))) unsigned*)g,
      (__attribute__((address_space(3))) unsigned*)lds, 16, 0, 0);
}

// ---------------- fp32 -> bf16 conversion of X and W ----------------
__global__ void cvt_all(const float4* __restrict__ X,
                        const float4* __restrict__ Wq,
                        const float4* __restrict__ Wk,
                        const float4* __restrict__ Wv,
                        ushort4* __restrict__ Xb,
                        ushort4* __restrict__ Wb) {
  int i = blockIdx.x * 256 + threadIdx.x;   // 1835008 total
  const float4* src; ushort4* dst; int idx;
  if (i < (MTOT * HID / 4)) {
    src = X; dst = Xb; idx = i;
  } else {
    int j = i - (MTOT * HID / 4);
    int sel = j >> 18;
    idx = j & 262143;
    src = (sel == 0) ? Wq : (sel == 1) ? Wk : Wv;
    dst = Wb + (size_t)sel * 262144;
  }
  float4 v = src[idx];
  ushort4 o;
  o.x = f2bf(v.x); o.y = f2bf(v.y); o.z = f2bf(v.z); o.w = f2bf(v.w);
  dst[idx] = o;
}

// ---------------- fused QKV projection GEMM ----------------
// BM=BN=128, 4 waves (2x2, 64x64 each). A: LDS triple-buffered (24 KB),
// XOR-swizzled, global_load_lds. B: DIRECT global->reg with 1-step register
// prefetch (L2-resident panel; line-coalesced). 1 barrier + vmcnt(6)/K-step.
// Q pre-scaled by 0.125*log2(e) (exp2-domain softmax downstream).
__global__ __launch_bounds__(256, 3) void qkv_gemm(
    const ushort* __restrict__ Xb,    // [4096][1024] bf16
    const ushort* __restrict__ Wb,    // [3072][1024] bf16 (Wq|Wk|Wv)
    const float* __restrict__ bq,
    const float* __restrict__ bk,
    const float* __restrict__ bv,
    ushort* __restrict__ Q,           // [B*H][S][64]
    ushort* __restrict__ K,           // [B*H][S][64]
    ushort* __restrict__ Vt)          // [B*H][64][S]
{
  __shared__ __attribute__((aligned(16))) ushort Al[3][128 * 32]; // 3x8KB

  int bid = blockIdx.x;               // 768 blocks
  // XCD swizzle with bm varying fastest: 4 concurrent M-blocks share a
  // B panel -> per-XCD working set ~3MB < 4MB L2.
  int xcd = bid & 7;
  int j = bid >> 3;                   // 0..95
  int bm = 4 * xcd + (j & 3);         // 0..31
  int bn = j >> 2;                    // 0..23
  int m0 = bm * 128, n0 = bn * 128;

  int tid = threadIdx.x;
  int wave = tid >> 6, lane = tid & 63;
  int g = lane >> 4, c = lane & 15;
  int wr = wave >> 1, wc = wave & 1;  // 2x2 waves, each 64x64 output

  // A staging (R6 proven scheme): 2 gload_lds/thread/step, XOR swizzle.
  int srow = tid >> 2, schunk = tid & 3;
  int ssw = (srow >> 1) & 3;
  const ushort* As0 = Xb + (size_t)(m0 + srow) * 1024 + ((schunk ^ ssw) << 3);
  const ushort* As1 = As0 + (size_t)64 * 1024;
  int soff = srow * 64 + schunk * 16;

  // B direct per-lane base: row n0 + wc*64 + n*16 + c, k-chunk g (8 elems).
  const ushort* Bg = Wb + (size_t)(n0 + wc * 64 + c) * 1024 + g * 8;

#define STAGE_A(bi, kk) do { \
    char* la_ = (char*)Al[bi]; \
    async16(la_ + soff,        As0 + (kk) * 32); \
    async16(la_ + 4096 + soff, As1 + (kk) * 32); } while (0)

#define LOADB(dst, kk) do { \
    _Pragma("unroll") \
    for (int n = 0; n < 4; ++n) \
      dst[n] = *(const bf16x8*)(Bg + (size_t)n * 16384 + (kk) * 32); } while (0)

  f32x4 acc[4][4] = {};
  int rsw = (c >> 1) & 3;             // read-side swizzle
  int ch = ((g ^ rsw) << 4);          // swizzled 16B chunk byte offset

  bf16x8 b0[4], b1[4];
  STAGE_A(0, 0);                      // A(0), A(1), b(0) in flight
  STAGE_A(1, 1);
  LOADB(b0, 0);
  __syncthreads();                    // full drain (vmcnt 0) + barrier

#define GSTEP(KS, CURBUF, STGBUF, BUSE, BLOAD) do {                       \
    __builtin_amdgcn_sched_barrier(0);                                    \
    __builtin_amdgcn_s_barrier();                                         \
    __builtin_amdgcn_sched_barrier(0);                                    \
    int kst_ = (KS) + 2 < 32 ? (KS) + 2 : 31;                             \
    int kld_ = (KS) + 1 < 32 ? (KS) + 1 : 31;                             \
    STAGE_A(STGBUF, kst_);                                                \
    LOADB(BLOAD, kld_);                                                   \
    const char* la_ = (const char*)Al[CURBUF];                            \
    bf16x8 a_[4];                                                         \
    _Pragma("unroll")                                                     \
    for (int m = 0; m < 4; ++m)                                           \
      a_[m] = *(const bf16x8*)(la_ + (wr * 64 + m * 16 + c) * 64 + ch);   \
    asm volatile("s_waitcnt vmcnt(6)" ::: "memory");                      \
    __builtin_amdgcn_sched_barrier(0);                                    \
    __builtin_amdgcn_s_setprio(1);                                        \
    _Pragma("unroll")                                                     \
    for (int m = 0; m < 4; ++m)                                           \
      _Pragma("unroll")                                                   \
      for (int n = 0; n < 4; ++n)                                         \
        acc[m][n] = __builtin_amdgcn_mfma_f32_16x16x32_bf16(              \
            a_[m], BUSE[n], acc[m][n], 0, 0, 0);                          \
    __builtin_amdgcn_s_setprio(0);                                        \
  } while (0)

  int cur = 0, nxt = 2;
  #pragma unroll 1
  for (int ks = 0; ks < 32; ks += 2) {
    GSTEP(ks, cur, nxt, b0, b1);
    cur = (cur == 2) ? 0 : cur + 1;
    nxt = (nxt == 2) ? 0 : nxt + 1;
    GSTEP(ks + 1, cur, nxt, b1, b0);
    cur = (cur == 2) ? 0 : cur + 1;
    nxt = (nxt == 2) ? 0 : nxt + 1;
  }
  asm volatile("s_waitcnt vmcnt(0)" ::: "memory");  // drain tail stages
#undef GSTEP
#undef STAGE_A
#undef LOADB

  int sel = n0 >> 10;                 // uniform per block (128 | 1024)
  const float* bp = (sel == 0) ? bq : (sel == 1) ? bk : bv;
  float scl = (sel == 0) ? 0.125f * LOG2E : 1.0f;

  #pragma unroll
  for (int n = 0; n < 4; ++n) {
    int nn = (n0 & 1023) + wc * 64 + n * 16 + c;
    float bias = bp[nn];
    int h = nn >> 6, d = nn & 63;
    #pragma unroll
    for (int m = 0; m < 4; ++m) {
      int rowg = m0 + wr * 64 + m * 16 + g * 4;
      int bb = rowg >> 10;
      int s = rowg & 1023;
      #pragma unroll
      for (int r = 0; r < 4; ++r) {
        float val = (acc[m][n][r] + bias) * scl;
        unsigned short ob = f2bf(val);
        if (sel == 0)
          Q[(size_t)((bb * 16 + h) * 1024 + s + r) * 64 + d] = ob;
        else if (sel == 1)
          K[(size_t)((bb * 16 + h) * 1024 + s + r) * 64 + d] = ob;
        else
          Vt[(size_t)((bb * 16 + h) * 64 + d) * 1024 + s + r] = ob;
      }
    }
  }
}

// Build two PV A-fragments from 16 P values (C-layout) — 8 cvt_pk + 4
// permlane32_swap, no LDS.
__device__ __forceinline__ void build_pa(const f32x16& p, bf16x8& pa0, bf16x8& pa1) {
  unsigned W0 = cvtpk(p[0],  p[1]);
  unsigned W1 = cvtpk(p[2],  p[3]);
  unsigned W2 = cvtpk(p[4],  p[5]);
  unsigned W3 = cvtpk(p[6],  p[7]);
  unsigned W4 = cvtpk(p[8],  p[9]);
  unsigned W5 = cvtpk(p[10], p[11]);
  unsigned W6 = cvtpk(p[12], p[13]);
  unsigned W7 = cvtpk(p[14], p[15]);
  pl32swap(W0, W2);
  pl32swap(W1, W3);
  pl32swap(W4, W6);
  pl32swap(W5, W7);
  union { unsigned u[4]; bf16x8 v; } a0, a1;
  a0.u[0] = W0; a0.u[1] = W1; a0.u[2] = W2; a0.u[3] = W3;
  a1.u[0] = W4; a1.u[1] = W5; a1.u[2] = W6; a1.u[3] = W7;
  pa0 = a0.v; pa1 = a1.v;
}

// ---------------- flash attention, 32x32 swapped orientation ----------------
// K: LDS triple-buffered (24 KB), XOR-swizzled. V: DIRECT global->reg
// (L2-hot via head-affinity), issued at iter top, vmcnt(2) before PV.
// 1 barrier/iter.
__global__ __launch_bounds__(256, 2) void attn(
    const ushort* __restrict__ Q,    // [B*H][S][64], pre-scaled 0.125*log2e
    const ushort* __restrict__ K,    // [B*H][S][64]
    const ushort* __restrict__ Vt,   // [B*H][64][S]
    const float* __restrict__ mask,  // [B][S]
    float* __restrict__ out)         // [B][S][1024]
{
  __shared__ __attribute__((aligned(16))) char k_lds[3][8192]; // K x3
  __shared__ float mask_s[SS];                                 // 4 KB

  int blk = blockIdx.x;           // 512
  int xcd = blk & 7;
  int j = blk >> 3;               // 0..63
  int bh = xcd * 8 + (j >> 3);    // 8 heads per XCD
  int qt = j & 7;
  int b = bh >> 4, h = bh & 15;
  int tid = threadIdx.x, wave = tid >> 6, lane = tid & 63;
  int r31 = lane & 31, hi = lane >> 5;
  int rsw = r31 & 7;
  int hib = hi << 4;
  int q0 = qt * 128 + wave * 32;

  const ushort* Qb = Q + (size_t)bh * SS * 64;
  const ushort* Kb = K + (size_t)bh * SS * 64;
  const ushort* Vb = Vt + (size_t)bh * 64 * SS;

  for (int i = tid; i < SS; i += 256) mask_s[i] = mask[b * SS + i] * LOG2E;

  bf16x8 qf[4];
  #pragma unroll
  for (int kp = 0; kp < 4; ++kp)
    qf[kp] = *(const bf16x8*)(Qb + (size_t)(q0 + r31) * 64 + kp * 16 + hi * 8);

  // K staging: 64 rows x 128B tile = 2 gload_lds/thread; XOR swizzle.
  int krow = tid >> 3;            // 0..31
  int gck = (tid & 7) ^ (krow & 7);
  const ushort* Ks0 = Kb + (size_t)krow * 64 + gck * 8;
  const ushort* Ks1 = Kb + (size_t)(krow + 32) * 64 + gck * 8;
  int soff = tid * 16;

#define STAGE_K(bi, t64) do { \
    char* lb_ = k_lds[bi]; \
    async16(lb_ + soff,        Ks0 + (size_t)(t64) * 4096); \
    async16(lb_ + 4096 + soff, Ks1 + (size_t)(t64) * 4096); } while (0)

  // V direct per-lane bases
  const ushort* Vg0 = Vb + (size_t)r31 * SS + hi * 8;
  const ushort* Vg1 = Vb + (size_t)(32 + r31) * SS + hi * 8;

  STAGE_K(0, 0);
  STAGE_K(1, 1);
  __syncthreads();                // drains vmcnt(0): K(0),K(1) + mask visible

  f32x16 o0 = (f32x16)0.0f, o1 = (f32x16)0.0f;
  float mrow = 0.f, lrow = 0.f;

  int cur = 0, nxt = 2;
  #pragma unroll 1
  for (int it = 0; it < 16; ++it) {
    __builtin_amdgcn_sched_barrier(0);
    __builtin_amdgcn_s_barrier();   // K(cur) visible; buf[nxt] free
    __builtin_amdgcn_sched_barrier(0);

    int kv = it * 64;
    // V loads for THIS iter (8x b128, L2-hot), in flight during QK+softmax
    bf16x8 vA[4], vC[4];
    #pragma unroll
    for (int kap = 0; kap < 4; ++kap) {
      vA[kap] = *(const bf16x8*)(Vg0 + kv + kap * 16);
      vC[kap] = *(const bf16x8*)(Vg1 + kv + kap * 16);
    }
    int kst = it + 2 < 16 ? it + 2 : 15;
    STAGE_K(nxt, kst);

    const char* kb0 = k_lds[cur];
    f32x16 s0 = (f32x16)0.0f, s1 = (f32x16)0.0f;
    __builtin_amdgcn_s_setprio(1);
    #pragma unroll
    for (int kp = 0; kp < 4; ++kp) {
      int ch = (((kp << 1) | hi) ^ rsw) << 4;
      bf16x8 ka = *(const bf16x8*)(kb0 + r31 * 128 + ch);
      bf16x8 kc = *(const bf16x8*)(kb0 + (32 + r31) * 128 + ch);
      s0 = __builtin_amdgcn_mfma_f32_32x32x16_bf16(ka, qf[kp], s0, 0, 0, 0);
      s1 = __builtin_amdgcn_mfma_f32_32x32x16_bf16(kc, qf[kp], s1, 0, 0, 0);
    }
    __builtin_amdgcn_s_setprio(0);

    #pragma unroll
    for (int sq = 0; sq < 4; ++sq) {
      f32x4 mk0 = *(const f32x4*)(&mask_s[kv + sq * 8 + hi * 4]);
      f32x4 mk1 = *(const f32x4*)(&mask_s[kv + 32 + sq * 8 + hi * 4]);
      #pragma unroll
      for (int r = 0; r < 4; ++r) {
        s0[sq * 4 + r] += mk0[r];
        s1[sq * 4 + r] += mk1[r];
      }
    }

    float mx = s0[0];
    #pragma unroll
    for (int i = 1; i < 16; ++i) mx = fmaxf(mx, s0[i]);
    #pragma unroll
    for (int i = 0; i < 16; ++i) mx = fmaxf(mx, s1[i]);
    mx = fmaxf(mx, __shfl_xor(mx, 32));

    if (!__all(mx <= mrow + 11.5416f)) {   // defer-max
      float mn = fmaxf(mrow, mx);
      float sc = exp2fast(mrow - mn);
      mrow = mn;
      lrow *= sc;
      #pragma unroll
      for (int i = 0; i < 16; ++i) {
        int qh = (i & 3) + 8 * (i >> 2);
        float scq = __uint_as_float((unsigned)__builtin_amdgcn_ds_bpermute(
            (qh << 2) + hib, (int)__float_as_uint(sc)));
        o0[i] *= scq; o1[i] *= scq;
      }
    }

    f32x16 p0, p1;
    float rs = 0.f;
    #pragma unroll
    for (int i = 0; i < 16; ++i) { float e = exp2fast(s0[i] - mrow); p0[i] = e; rs += e; }
    #pragma unroll
    for (int i = 0; i < 16; ++i) { float e = exp2fast(s1[i] - mrow); p1[i] = e; rs += e; }
    rs += __shfl_xor(rs, 32);
    lrow += rs;

    asm volatile("s_waitcnt vmcnt(2)" ::: "memory");  // V landed; K-stage in flight
    __builtin_amdgcn_sched_barrier(0);

    #pragma unroll
    for (int T = 0; T < 2; ++T) {
      bf16x8 pa0, pa1;
      build_pa(T ? p1 : p0, pa0, pa1);
      __builtin_amdgcn_s_setprio(1);
      #pragma unroll
      for (int kh = 0; kh < 2; ++kh) {
        int kap = 2 * T + kh;
        bf16x8 pf = kh ? pa1 : pa0;
        o0 = __builtin_amdgcn_mfma_f32_32x32x16_bf16(pf, vA[kap], o0, 0, 0, 0);
        o1 = __builtin_amdgcn_mfma_f32_32x32x16_bf16(pf, vC[kap], o1, 0, 0, 0);
      }
      __builtin_amdgcn_s_setprio(0);
    }

    cur = (cur == 2) ? 0 : cur + 1;
    nxt = (nxt == 2) ? 0 : nxt + 1;
  }
#undef STAGE_K
  asm volatile("s_waitcnt vmcnt(0)" ::: "memory");

  float inv = 1.0f / lrow;
  #pragma unroll
  for (int i = 0; i < 16; ++i) {
    int qh = (i & 3) + 8 * (i >> 2);
    float li = __uint_as_float((unsigned)__builtin_amdgcn_ds_bpermute(
        (qh << 2) + hib, (int)__float_as_uint(inv)));
    int row = q0 + qh + 4 * hi;
    float* op = out + (size_t)(b * SS + row) * 1024 + h * 64 + r31;
    op[0]  = o0[i] * li;
    op[32] = o1[i] * li;
  }
}

extern "C" void kernel_launch(void* const* d_in, const int* in_sizes, int n_in,
                              void* d_out, int out_size, void* d_ws, size_t ws_size,
                              hipStream_t stream) {
  const float* hs   = (const float*)d_in[0];
  const float* mask = (const float*)d_in[1];
  const float* Wq   = (const float*)d_in[2];
  const float* bq   = (const float*)d_in[3];
  const float* Wk   = (const float*)d_in[4];
  const float* bk   = (const float*)d_in[5];
  const float* Wv   = (const float*)d_in[6];
  const float* bv   = (const float*)d_in[7];
  float* out = (float*)d_out;

  char* ws = (char*)d_ws;
  ushort* Xb = (ushort*)(ws);                    // 8 MB  [4096][1024]
  ushort* Wb = (ushort*)(ws + (8u  << 20));      // 6 MB  [3072][1024]
  ushort* Qp = (ushort*)(ws + (14u << 20));      // 8 MB  [64][1024][64]
  ushort* Kp = (ushort*)(ws + (22u << 20));      // 8 MB  [64][1024][64]
  ushort* Vt = (ushort*)(ws + (30u << 20));      // 8 MB  [64][64][1024]

  cvt_all<<<7168, 256, 0, stream>>>((const float4*)hs, (const float4*)Wq,
                                    (const float4*)Wk, (const float4*)Wv,
                                    (ushort4*)Xb, (ushort4*)Wb);
  qkv_gemm<<<768, 256, 0, stream>>>(Xb, Wb, bq, bk, bv, Qp, Kp, Vt);
  attn<<<512, 256, 0, stream>>>(Qp, Kp, Vt, mask, out);
}

// Round 11
// 85.413 us; speedup vs baseline: 1.3640x; 1.3640x over previous
//
#include <hip/hip_runtime.h>
#include <hip/hip_bf16.h>
#include <stdint.h>

#define NH 16
#define HID 1024
#define HD 64
#define NB 4
#define SS 1024
#define MTOT (NB*SS)   // 4096

typedef __attribute__((ext_vector_type(8))) short bf16x8;
typedef __attribute__((ext_vector_type(4))) float f32x4;
typedef __attribute__((ext_vector_type(16))) float f32x16;

#define LOG2E 1.44269504088896f

__device__ __forceinline__ unsigned short f2bf(float f) {
  union { float f; unsigned u; } v; v.f = f;
  unsigned u = v.u;
  return (unsigned short)((u + 0x7FFFu + ((u >> 16) & 1u)) >> 16);
}

__device__ __forceinline__ unsigned cvtpk(float lo, float hi) {
  unsigned r;
  asm("v_cvt_pk_bf16_f32 %0, %1, %2" : "=v"(r) : "v"(lo), "v"(hi));
  return r;
}

__device__ __forceinline__ void pl32swap(unsigned &a, unsigned &b) {
  asm("v_permlane32_swap_b32 %0, %1" : "+v"(a), "+v"(b));
}

__device__ __forceinline__ float exp2fast(float x) {
  float r;
  asm("v_exp_f32 %0, %1" : "=v"(r) : "v"(x));
  return r;
}

__device__ __forceinline__ void async16(void* lds, const void* g) {
  __builtin_amdgcn_global_load_lds(
      (const __attribute__((address_space(1))) unsigned*)g,
      (__attribute__((address_space(3))) unsigned*)lds, 16, 0, 0);
}

// ---------------- fp32 -> bf16 conversion of X and W ----------------
__global__ void cvt_all(const float4* __restrict__ X,
                        const float4* __restrict__ Wq,
                        const float4* __restrict__ Wk,
                        const float4* __restrict__ Wv,
                        ushort4* __restrict__ Xb,
                        ushort4* __restrict__ Wb) {
  int i = blockIdx.x * 256 + threadIdx.x;   // 1835008 total
  const float4* src; ushort4* dst; int idx;
  if (i < (MTOT * HID / 4)) {
    src = X; dst = Xb; idx = i;
  } else {
    int j = i - (MTOT * HID / 4);
    int sel = j >> 18;
    idx = j & 262143;
    src = (sel == 0) ? Wq : (sel == 1) ? Wk : Wv;
    dst = Wb + (size_t)sel * 262144;
  }
  float4 v = src[idx];
  ushort4 o;
  o.x = f2bf(v.x); o.y = f2bf(v.y); o.z = f2bf(v.z); o.w = f2bf(v.w);
  dst[idx] = o;
}

// ---------------- fused QKV projection GEMM (R6 config, proven 45.5us) ----
// BK=32 TRIPLE-buffered, 1 barrier/step, STAGE after barrier, counted vmcnt.
// Q pre-scaled by 0.125*log2(e) so attention softmax runs in exp2 domain.
__global__ __launch_bounds__(256) void qkv_gemm(
    const ushort* __restrict__ Xb,    // [4096][1024] bf16
    const ushort* __restrict__ Wb,    // [3072][1024] bf16 (Wq|Wk|Wv)
    const float* __restrict__ bq,
    const float* __restrict__ bk,
    const float* __restrict__ bv,
    ushort* __restrict__ Q,           // [B*H][S][64]
    ushort* __restrict__ K,           // [B*H][S][64]
    ushort* __restrict__ Vt)          // [B*H][64][S]
{
  __shared__ __attribute__((aligned(16))) ushort Al[3][128 * 32]; // 3x8KB
  __shared__ __attribute__((aligned(16))) ushort Bl[3][128 * 32]; // 3x8KB

  int bid = blockIdx.x;               // 768 blocks
  int swz = (bid & 7) * 96 + (bid >> 3);  // XCD swizzle (768 % 8 == 0)
  const int nbn = 3072 / 128;         // 24
  int bm = swz / nbn, bn = swz % nbn;
  int m0 = bm * 128, n0 = bn * 128;

  int tid = threadIdx.x;
  int wave = tid >> 6, lane = tid & 63;
  int g = lane >> 4, c = lane & 15;
  int wr = wave >> 1, wc = wave & 1;  // 2x2 waves, each 64x64 output

  // staging: per K-step each thread issues 2 A-loads + 2 B-loads (16B).
  // LDS dest linear; bank swizzle via XOR on the GLOBAL 16B-chunk index.
  int srow = tid >> 2;                // 0..63
  int schunk = tid & 3;
  int ssw = (srow >> 1) & 3;
  const ushort* Asrc0 = Xb + (size_t)(m0 + srow) * 1024 + ((schunk ^ ssw) << 3);
  const ushort* Asrc1 = Xb + (size_t)(m0 + 64 + srow) * 1024 + ((schunk ^ ssw) << 3);
  const ushort* Bsrc0 = Wb + (size_t)(n0 + srow) * 1024 + ((schunk ^ ssw) << 3);
  const ushort* Bsrc1 = Wb + (size_t)(n0 + 64 + srow) * 1024 + ((schunk ^ ssw) << 3);
  int soff = srow * 64 + schunk * 16;

#define GSTAGE(bi) do {                                   \
    char* la_ = (char*)Al[bi]; char* lb_ = (char*)Bl[bi]; \
    async16(la_ + soff,        Asrc0);                    \
    async16(la_ + 4096 + soff, Asrc1);                    \
    async16(lb_ + soff,        Bsrc0);                    \
    async16(lb_ + 4096 + soff, Bsrc1);                    \
    Asrc0 += 32; Asrc1 += 32; Bsrc0 += 32; Bsrc1 += 32;   \
  } while (0)

  f32x4 acc[4][4] = {};
  int rsw = (c >> 1) & 3;             // read-side swizzle
  int ch = ((g ^ rsw) << 4);          // swizzled 16B chunk byte offset

  GSTAGE(0);                          // prologue: 2 steps in flight
  GSTAGE(1);

  int cur = 0, nxt = 2;
  for (int ks = 0; ks < 32; ++ks) {
    if (ks < 31) {
      asm volatile("s_waitcnt vmcnt(4)" ::: "memory");  // cur landed, next in flight
    } else {
      asm volatile("s_waitcnt vmcnt(0)" ::: "memory");
    }
    __builtin_amdgcn_sched_barrier(0);
    __builtin_amdgcn_s_barrier();     // all waves: cur tile complete
    __builtin_amdgcn_sched_barrier(0);
    if (ks < 30) GSTAGE(nxt);         // safe: all waves past reads of buf[nxt]

    const char* la = (const char*)Al[cur];
    const char* lb = (const char*)Bl[cur];
    bf16x8 a[4], b[4];
    #pragma unroll
    for (int m = 0; m < 4; ++m)
      a[m] = *(const bf16x8*)(la + (wr * 64 + m * 16 + c) * 64 + ch);
    #pragma unroll
    for (int n = 0; n < 4; ++n)
      b[n] = *(const bf16x8*)(lb + (wc * 64 + n * 16 + c) * 64 + ch);
    __builtin_amdgcn_s_setprio(1);
    #pragma unroll
    for (int m = 0; m < 4; ++m)
      #pragma unroll
      for (int n = 0; n < 4; ++n)
        acc[m][n] = __builtin_amdgcn_mfma_f32_16x16x32_bf16(a[m], b[n], acc[m][n], 0, 0, 0);
    __builtin_amdgcn_s_setprio(0);

    cur = (cur == 2) ? 0 : cur + 1;
    nxt = (nxt == 2) ? 0 : nxt + 1;
  }
#undef GSTAGE

  int sel = n0 >> 10;
  const float* bp = (sel == 0) ? bq : (sel == 1) ? bk : bv;
  float scl = (sel == 0) ? 0.125f * LOG2E : 1.0f;

  #pragma unroll
  for (int n = 0; n < 4; ++n) {
    int nn = (n0 & 1023) + wc * 64 + n * 16 + c;
    float bias = bp[nn];
    int h = nn >> 6, d = nn & 63;
    #pragma unroll
    for (int m = 0; m < 4; ++m) {
      int rowg = m0 + wr * 64 + m * 16 + g * 4;
      int bb = rowg >> 10;
      int s = rowg & 1023;
      #pragma unroll
      for (int r = 0; r < 4; ++r) {
        float val = (acc[m][n][r] + bias) * scl;
        unsigned short ob = f2bf(val);
        if (sel == 0)
          Q[(size_t)((bb * 16 + h) * 1024 + s + r) * 64 + d] = ob;
        else if (sel == 1)
          K[(size_t)((bb * 16 + h) * 1024 + s + r) * 64 + d] = ob;
        else
          Vt[(size_t)((bb * 16 + h) * 64 + d) * 1024 + s + r] = ob;
      }
    }
  }
}

// Build two PV A-fragments from 16 P values (C-layout) — 8 cvt_pk + 4
// permlane32_swap, no LDS.
__device__ __forceinline__ void build_pa(const f32x16& p, bf16x8& pa0, bf16x8& pa1) {
  unsigned W0 = cvtpk(p[0],  p[1]);
  unsigned W1 = cvtpk(p[2],  p[3]);
  unsigned W2 = cvtpk(p[4],  p[5]);
  unsigned W3 = cvtpk(p[6],  p[7]);
  unsigned W4 = cvtpk(p[8],  p[9]);
  unsigned W5 = cvtpk(p[10], p[11]);
  unsigned W6 = cvtpk(p[12], p[13]);
  unsigned W7 = cvtpk(p[14], p[15]);
  pl32swap(W0, W2);
  pl32swap(W1, W3);
  pl32swap(W4, W6);
  pl32swap(W5, W7);
  union { unsigned u[4]; bf16x8 v; } a0, a1;
  a0.u[0] = W0; a0.u[1] = W1; a0.u[2] = W2; a0.u[3] = W3;
  a1.u[0] = W4; a1.u[1] = W5; a1.u[2] = W6; a1.u[3] = W7;
  pa0 = a0.v; pa1 = a1.v;
}

// ---------------- flash attention, 32x32 swapped orientation ----------------
// 512-thread blocks: 8 waves x 32 q-rows = 256 q-rows/block; grid 256 =
// EXACTLY 1 block/CU. K/V tile (16KB/iter) amortized over 2x the q-rows;
// staging = 2 loads/thread. Triple-buffered, 1 barrier/iter, counted vmcnt.
__global__ __launch_bounds__(512) void attn(
    const ushort* __restrict__ Q,    // [B*H][S][64], pre-scaled 0.125*log2e
    const ushort* __restrict__ K,    // [B*H][S][64]
    const ushort* __restrict__ Vt,   // [B*H][64][S]
    const float* __restrict__ mask,  // [B][S]
    float* __restrict__ out)         // [B][S][1024]
{
  __shared__ __attribute__((aligned(16))) char kv_lds[3][16384]; // [K 8K][V 8K] x3
  __shared__ float mask_s[SS];                                   // 4 KB (log2-domain)

  int blk = blockIdx.x;           // 256
  int xcd = blk & 7;
  int j = blk >> 3;               // 0..31
  int bh = xcd * 8 + (j >> 2);    // 8 heads per XCD; 4 blocks per head
  int qt = j & 3;
  int b = bh >> 4, h = bh & 15;
  int tid = threadIdx.x, wave = tid >> 6, lane = tid & 63;
  int r31 = lane & 31, hi = lane >> 5;
  int rsw = r31 & 7;
  int hib = hi << 4;
  int q0 = qt * 256 + wave * 32;

  const ushort* Qb = Q + (size_t)bh * SS * 64;
  const ushort* Kb = K + (size_t)bh * SS * 64;
  const ushort* Vb = Vt + (size_t)bh * 64 * SS;

  // mask to LDS, pre-multiplied by log2e (off the vmcnt path in the loop)
  for (int i = tid; i < SS; i += 512) mask_s[i] = mask[b * SS + i] * LOG2E;

  bf16x8 qf[4];
  #pragma unroll
  for (int kp = 0; kp < 4; ++kp)
    qf[kp] = *(const bf16x8*)(Qb + (size_t)(q0 + r31) * 64 + kp * 16 + hi * 8);

  // staging: waves 0-3 -> K tile (8KB), waves 4-7 -> V tile (8KB).
  // 2 x 16B loads per thread. LDS dest linear; XOR bank swizzle via the
  // GLOBAL chunk index (chunk' = chunk ^ (row&7)); reads use same XOR.
  int srow = lane >> 3;           // 0..7
  int spos = lane & 7;
  bool isK = (wave < 4);
  int w4 = isK ? wave : wave - 4;
  const ushort* sptr[2];
  int soff[2];
  #pragma unroll
  for (int j2 = 0; j2 < 2; ++j2) {
    int row = w4 * 16 + j2 * 8 + srow;                 // 0..63
    soff[j2] = (isK ? 0 : 8192) + w4 * 2048 + j2 * 1024 + lane * 16;
    if (isK)
      sptr[j2] = Kb + (size_t)row * 64 + ((spos ^ srow) << 3);
    else
      sptr[j2] = Vb + (size_t)row * SS + ((spos ^ srow) << 3);
  }
  const int sstep = isK ? 64 * 64 : 64;

#define STAGE(bufidx) do {                              \
    char* lb_ = kv_lds[bufidx];                         \
    async16(lb_ + soff[0], sptr[0]);                    \
    async16(lb_ + soff[1], sptr[1]);                    \
    sptr[0] += sstep; sptr[1] += sstep;                 \
  } while (0)

  __syncthreads();                // mask_s visible to all waves
  STAGE(0);                       // prologue: 2 tiles in flight
  STAGE(1);

  f32x16 o0 = (f32x16)0.0f, o1 = (f32x16)0.0f;
  float mrow = 0.f, lrow = 0.f;

  int cur = 0, nxt = 2;
  for (int it = 0; it < 16; ++it) {
    if (it < 15) {
      asm volatile("s_waitcnt vmcnt(2)" ::: "memory");
    } else {
      asm volatile("s_waitcnt vmcnt(0)" ::: "memory");
    }
    __builtin_amdgcn_sched_barrier(0);
    __builtin_amdgcn_s_barrier();
    __builtin_amdgcn_sched_barrier(0);
    if (it < 14) STAGE(nxt);

    const char* kb0 = kv_lds[cur];
    const char* vb0 = kv_lds[cur] + 8192;

    f32x16 s0 = (f32x16)0.0f, s1 = (f32x16)0.0f;
    __builtin_amdgcn_s_setprio(1);
    #pragma unroll
    for (int kp = 0; kp < 4; ++kp) {
      int ch = (((kp << 1) | hi) ^ rsw) << 4;
      bf16x8 ka = *(const bf16x8*)(kb0 + r31 * 128 + ch);
      bf16x8 kc = *(const bf16x8*)(kb0 + (32 + r31) * 128 + ch);
      s0 = __builtin_amdgcn_mfma_f32_32x32x16_bf16(ka, qf[kp], s0, 0, 0, 0);
      s1 = __builtin_amdgcn_mfma_f32_32x32x16_bf16(kc, qf[kp], s1, 0, 0, 0);
    }
    __builtin_amdgcn_s_setprio(0);

    int kv = it * 64;
    #pragma unroll
    for (int sq = 0; sq < 4; ++sq) {
      f32x4 mk0 = *(const f32x4*)(&mask_s[kv + sq * 8 + hi * 4]);
      f32x4 mk1 = *(const f32x4*)(&mask_s[kv + 32 + sq * 8 + hi * 4]);
      #pragma unroll
      for (int r = 0; r < 4; ++r) {
        s0[sq * 4 + r] += mk0[r];
        s1[sq * 4 + r] += mk1[r];
      }
    }

    float mx = s0[0];
    #pragma unroll
    for (int i = 1; i < 16; ++i) mx = fmaxf(mx, s0[i]);
    #pragma unroll
    for (int i = 0; i < 16; ++i) mx = fmaxf(mx, s1[i]);
    mx = fmaxf(mx, __shfl_xor(mx, 32));

    if (!__all(mx <= mrow + 11.5416f)) {   // defer-max
      float mn = fmaxf(mrow, mx);
      float sc = exp2fast(mrow - mn);
      mrow = mn;
      lrow *= sc;
      #pragma unroll
      for (int i = 0; i < 16; ++i) {
        int qh = (i & 3) + 8 * (i >> 2);
        float scq = __uint_as_float((unsigned)__builtin_amdgcn_ds_bpermute(
            (qh << 2) + hib, (int)__float_as_uint(sc)));
        o0[i] *= scq; o1[i] *= scq;
      }
    }

    f32x16 p0, p1;
    float rs = 0.f;
    #pragma unroll
    for (int i = 0; i < 16; ++i) { float e = exp2fast(s0[i] - mrow); p0[i] = e; rs += e; }
    #pragma unroll
    for (int i = 0; i < 16; ++i) { float e = exp2fast(s1[i] - mrow); p1[i] = e; rs += e; }
    rs += __shfl_xor(rs, 32);
    lrow += rs;

    #pragma unroll
    for (int T = 0; T < 2; ++T) {
      bf16x8 pa0, pa1;
      build_pa(T ? p1 : p0, pa0, pa1);
      __builtin_amdgcn_s_setprio(1);
      #pragma unroll
      for (int kh = 0; kh < 2; ++kh) {
        int kap = 2 * T + kh;
        int ch = (((kap << 1) | hi) ^ rsw) << 4;
        bf16x8 va = *(const bf16x8*)(vb0 + r31 * 128 + ch);
        bf16x8 vc = *(const bf16x8*)(vb0 + (32 + r31) * 128 + ch);
        bf16x8 pf = kh ? pa1 : pa0;
        o0 = __builtin_amdgcn_mfma_f32_32x32x16_bf16(pf, va, o0, 0, 0, 0);
        o1 = __builtin_amdgcn_mfma_f32_32x32x16_bf16(pf, vc, o1, 0, 0, 0);
      }
      __builtin_amdgcn_s_setprio(0);
    }

    cur = (cur == 2) ? 0 : cur + 1;
    nxt = (nxt == 2) ? 0 : nxt + 1;
  }
#undef STAGE

  float inv = 1.0f / lrow;
  #pragma unroll
  for (int i = 0; i < 16; ++i) {
    int qh = (i & 3) + 8 * (i >> 2);
    float li = __uint_as_float((unsigned)__builtin_amdgcn_ds_bpermute(
        (qh << 2) + hib, (int)__float_as_uint(inv)));
    int row = q0 + qh + 4 * hi;
    float* op = out + (size_t)(b * SS + row) * 1024 + h * 64 + r31;
    op[0]  = o0[i] * li;
    op[32] = o1[i] * li;
  }
}

extern "C" void kernel_launch(void* const* d_in, const int* in_sizes, int n_in,
                              void* d_out, int out_size, void* d_ws, size_t ws_size,
                              hipStream_t stream) {
  const float* hs   = (const float*)d_in[0];
  const float* mask = (const float*)d_in[1];
  const float* Wq   = (const float*)d_in[2];
  const float* bq   = (const float*)d_in[3];
  const float* Wk   = (const float*)d_in[4];
  const float* bk   = (const float*)d_in[5];
  const float* Wv   = (const float*)d_in[6];
  const float* bv   = (const float*)d_in[7];
  float* out = (float*)d_out;

  char* ws = (char*)d_ws;
  ushort* Xb = (ushort*)(ws);                    // 8 MB  [4096][1024]
  ushort* Wb = (ushort*)(ws + (8u  << 20));      // 6 MB  [3072][1024]
  ushort* Qp = (ushort*)(ws + (14u << 20));      // 8 MB  [64][1024][64]
  ushort* Kp = (ushort*)(ws + (22u << 20));      // 8 MB  [64][1024][64]
  ushort* Vt = (ushort*)(ws + (30u << 20));      // 8 MB  [64][64][1024]

  cvt_all<<<7168, 256, 0, stream>>>((const float4*)hs, (const float4*)Wq,
                                    (const float4*)Wk, (const float4*)Wv,
                                    (ushort4*)Xb, (ushort4*)Wb);
  qkv_gemm<<<768, 256, 0, stream>>>(Xb, Wb, bq, bk, bv, Qp, Kp, Vt);
  attn<<<256, 512, 0, stream>>>(Qp, Kp, Vt, mask, out);
}